// Round 1
// 132.353 us; speedup vs baseline: 1.0584x; 1.0584x over previous
//
#include <hip/hip_runtime.h>
#include <math.h>

#define BB 4
#define CC 256
#define LL 4096
#define DD 32   // q/k channels
#define LOG2E 1.44269504088896f

typedef __attribute__((ext_vector_type(8))) short short8;   // 8 bf16 (4 VGPRs)
typedef __attribute__((ext_vector_type(4))) short short4v;
typedef __attribute__((ext_vector_type(4))) float f32x4;
typedef __attribute__((ext_vector_type(4))) unsigned int uint4v;
typedef __attribute__((ext_vector_type(2))) unsigned int uint2v;

// raw workgroup barrier: waits LDS ops only — global prefetches stay in flight
#define BARRIER() asm volatile("s_waitcnt lgkmcnt(0)\n\ts_barrier" ::: "memory")

__device__ inline unsigned short f2bf(float f) {
  union { float f; unsigned u; } v; v.f = f;
  unsigned r = v.u + 0x7fffu + ((v.u >> 16) & 1u);  // RNE
  return (unsigned short)(r >> 16);
}

__device__ inline float fast_exp2(float x) {
#if __has_builtin(__builtin_amdgcn_exp2f)
  return __builtin_amdgcn_exp2f(x);
#else
  return exp2f(x);
#endif
}

// natural key p -> kT storage row within its 32-key group (P C-layout == PV B-layout)
__device__ __host__ inline int sigma32(int p) {
  const int q4 = (p >> 3) & 3, u = p & 7;
  return 16 * (u >> 2) + 4 * q4 + (u & 3);
}

// ---------------- kernel 0: W -> bf16 MFMA-fragment-linear layout ----------------
// wf[ot(20)][ks(8)][lane(64)][8]; Wq rows pre-scaled by log2(e).
__global__ __launch_bounds__(256) void wprep_kernel(
    const float* __restrict__ Wq, const float* __restrict__ Wk, const float* __restrict__ Wv,
    unsigned short* __restrict__ wf)
{
  const int t = threadIdx.x;
  const int ot = blockIdx.x >> 1;           // 0..19
  const int rep = blockIdx.x & 1;
  const int lane = t & 63, cl = lane & 15, q4 = lane >> 4;
  const int ks = (t >> 6) + 4 * rep;        // 0..7
  const int o = ot * 16 + cl;
  const int c = ks * 32 + q4 * 8;
  const float* src = (o < 32) ? (Wq + o * CC) : (o < 64) ? (Wk + (o - 32) * CC)
                                              : (Wv + (o - 64) * CC);
  const float sc = (o < 32) ? LOG2E : 1.0f;
  unsigned short p[8];
  #pragma unroll
  for (int j = 0; j < 8; ++j) p[j] = f2bf(src[c + j] * sc);
  uint4v u;
  u.x = (unsigned)p[0] | ((unsigned)p[1] << 16);
  u.y = (unsigned)p[2] | ((unsigned)p[3] << 16);
  u.z = (unsigned)p[4] | ((unsigned)p[5] << 16);
  u.w = (unsigned)p[6] | ((unsigned)p[7] << 16);
  *(uint4v*)(wf + ((size_t)(ot * 8 + ks) * 64 + lane) * 8) = u;
}

// ---------------- kernel 1: fused transpose + QKV projection (R6-proven) ----------------
// grid 512 = (b, it 32-i tile) XCD-affine; 512 thr = 8 waves (wi 16-i, wo 5-ot).
__global__ __launch_bounds__(512, 4) void qkv_kernel(
    const float* __restrict__ x, const unsigned short* __restrict__ wf,
    const float* __restrict__ bq, const float* __restrict__ bk, const float* __restrict__ bv,
    unsigned short* __restrict__ qT, unsigned short* __restrict__ kT,
    unsigned short* __restrict__ vf)
{
  __shared__ union {
    float xl[32 * 261];                                   // [i][c] odd stride
    struct {
      unsigned short qk[32 * 72];                         // [i][o 0..63]
      __align__(16) unsigned short v[256 * 40];           // [ch][key 0..31] pad-40
    } ep;
  } sm;

  const int t = threadIdx.x;
  const int lane = t & 63, cl = lane & 15, q4 = lane >> 4;
  const int blk = blockIdx.x;
  const int b  = (blk & 7) >> 1;                          // XCD-batch affinity
  const int it = ((blk >> 3) << 1) + (blk & 1);           // 0..127
  const int i0 = it * 32;

  // ---- stage x: coalesced 128B rows -> LDS transposed ----
  {
    const int ln8 = t & 7;
    #pragma unroll
    for (int p = 0; p < 4; ++p) {
      const int c = (t >> 3) + 64 * p;
      const f32x4 v = *(const f32x4*)(x + ((size_t)(b * CC + c)) * LL + i0 + ln8 * 4);
      #pragma unroll
      for (int k = 0; k < 4; ++k) sm.xl[(ln8 * 4 + k) * 261 + c] = v[k];
    }
  }
  __syncthreads();

  // ---- GEMM: wave (wi,wo): 80 o-rows x 16 i x 256 c ----
  const int wi = (t >> 6) & 1, wo = t >> 7;
  const f32x4 zero = {0.f, 0.f, 0.f, 0.f};
  f32x4 acc[5];
  #pragma unroll
  for (int u = 0; u < 5; ++u) acc[u] = zero;

  for (int ks = 0; ks < 8; ++ks) {
    unsigned short p[8];
    #pragma unroll
    for (int j = 0; j < 8; ++j)
      p[j] = f2bf(sm.xl[(16 * wi + cl) * 261 + ks * 32 + q4 * 8 + j]);
    union { short8 s; uint4v u; } bfr;
    bfr.u.x = (unsigned)p[0] | ((unsigned)p[1] << 16);
    bfr.u.y = (unsigned)p[2] | ((unsigned)p[3] << 16);
    bfr.u.z = (unsigned)p[4] | ((unsigned)p[5] << 16);
    bfr.u.w = (unsigned)p[6] | ((unsigned)p[7] << 16);
    #pragma unroll
    for (int u = 0; u < 5; ++u) {
      const short8 a = *(const short8*)(wf + ((size_t)((wo * 5 + u) * 8 + ks) * 64 + lane) * 8);
      acc[u] = __builtin_amdgcn_mfma_f32_16x16x32_bf16(a, bfr.s, acc[u], 0, 0, 0);
    }
  }
  __syncthreads();   // xl dead; alias as ep

  // ---- stage outputs ----
  #pragma unroll
  for (int u = 0; u < 5; ++u) {
    const int g = wo * 5 + u;
    if (g < 4) {     // q (g<2) / k
      short4v pk;
      #pragma unroll
      for (int r = 0; r < 4; ++r) {
        const int o = 16 * g + 4 * q4 + r;
        const float v = acc[u][r] + ((o < 32) ? bq[o] * LOG2E : bk[o - 32]);
        pk[r] = (short)f2bf(v);
      }
      *(short4v*)&sm.ep.qk[(16 * wi + cl) * 72 + 16 * g + 4 * q4] = pk;
    } else {
      #pragma unroll
      for (int r = 0; r < 4; ++r) {
        const int ch = 16 * (g - 4) + 4 * q4 + r;
        sm.ep.v[ch * 40 + 16 * wi + cl] = f2bf(acc[u][r] + bv[ch]);
      }
    }
  }
  __syncthreads();

  // ---- coalesced stores ----
  if (t < 64) {
    const int i = t >> 1, which = t & 1;
    const int gi = i0 + i;
    const unsigned short* srcp = &sm.ep.qk[i * 72 + which * 32];
    uint4v d0 = *(const uint4v*)(srcp + 0);
    uint4v d1 = *(const uint4v*)(srcp + 8);
    uint4v d2 = *(const uint4v*)(srcp + 16);
    uint4v d3 = *(const uint4v*)(srcp + 24);
    unsigned short* dst;
    if (which == 0) {
      dst = qT + ((size_t)b * LL + gi) * DD;
    } else {
      const int row = (gi & ~31) + sigma32(gi & 31);
      dst = kT + ((size_t)b * LL + row) * DD;
    }
    *(uint4v*)dst = d0; *(uint4v*)(dst + 8) = d1;
    *(uint4v*)(dst + 16) = d2; *(uint4v*)(dst + 24) = d3;
  }
  // vf: this block covers kk = it&1 of jt = it>>1: 16 frags x 1KB
  const int kk = it & 1, jt = it >> 1;
  #pragma unroll
  for (int rep = 0; rep < 2; ++rep) {
    const int slot = t + 512 * rep;
    const int fl = slot >> 6, l2 = slot & 63;
    const int cl2 = l2 & 15, q42 = l2 >> 4;
    const int m4 = fl >> 2, mt = fl & 3;
    const int fg = 8 * m4 + 4 * kk + mt;
    const int ch = 64 * m4 + 16 * mt + cl2;
    const uint4v d = *(const uint4v*)&sm.ep.v[ch * 40 + q42 * 8];
    *(uint4v*)(vf + (((size_t)(b * 64 + jt)) * 32 + fg) * 512 + l2 * 8) = d;
  }
}

// ---------------- kernel 2: flash attention, 64-q blocks, 1 block/CU ----------------
// R7: 64 queries per block (nt 0..3) -> per-XCD L2 va traffic halves (33us -> 17us floor).
// grid 256 = (b, it 64-q tile); 512 thr = 8 waves.
// Superstep = 256 keys. Phase A: wave w computes S/exp for its 32-key group kk=w
// (2 kb frags x 4 q-tiles) -> P LDS (dbuf, conflict-free 8B/lane layout).
// Phase B: wave (m4 = w&3: 64 ch, kh = w>>2: 128-key half) PV: 4 kk x 4 mt x 4 nt MFMAs.
// l: per-lane partials only in-loop (no cross-lane ops); reduced once in epilogue.
__global__ __launch_bounds__(512, 2) void attn_kernel(
    const unsigned short* __restrict__ qT, const unsigned short* __restrict__ kT,
    const unsigned short* __restrict__ vf, const float* __restrict__ x,
    const float* __restrict__ gamma_p, float* __restrict__ out)
{
  __shared__ union __align__(16) {
    unsigned short P[2][8][4][2][64][4];  // [buf][kk][nt][half][lane][j]  64 KB
    float Om[4][16][64][4];               // [m4][mt*4+nt][lane][r]        64 KB
  } sm;
  __shared__ float l_lds[8][4][64];       // [wave][nt][lane] partial l

  const int t = threadIdx.x;
  const int w = t >> 6, lane = t & 63, cl = lane & 15, q4 = lane >> 4;
  const int m4 = w & 3, kh = w >> 2;
  const int blk = blockIdx.x;
  const int b  = (blk & 7) >> 1;                          // matches qkv affinity
  const int it = ((blk >> 3) << 1) + (blk & 1);           // 0..63
  const int i0 = it * 64;

  // persistent Q B-frags (4 16-query tiles)
  short8 qa[4];
  #pragma unroll
  for (int nt = 0; nt < 4; ++nt)
    qa[nt] = *(const short8*)(qT + ((size_t)b * LL + i0 + 16 * nt + cl) * DD + q4 * 8);

  const f32x4 zero = {0.f, 0.f, 0.f, 0.f};
  f32x4 O[4][4];                          // [mt][nt]: ch 64*m4+16*mt, q 16*nt
  #pragma unroll
  for (int mt = 0; mt < 4; ++mt)
    #pragma unroll
    for (int nt = 0; nt < 4; ++nt) O[mt][nt] = zero;
  float l_r[4] = {0.f, 0.f, 0.f, 0.f};

  // phase A source: kT rows [ss*256 + 32*w + 16*h), sigma-permuted
  const unsigned short* kbase = kT + ((size_t)b * LL + 32 * w + cl) * DD + q4 * 8;
  // phase B source: frag f = (ss*4 + (kk>>1))*32 + 8*m4 + 4*(kk&1) + mt
  const unsigned short* vroot = vf + ((size_t)(b * 64)) * 32 * 512 + lane * 8;

  short8 kb[2];
  #pragma unroll
  for (int h = 0; h < 2; ++h)
    kb[h] = *(const short8*)(kbase + (size_t)(16 * h) * DD);

  short8 va[2][4];                        // [slot e&1][mt]
  #pragma unroll
  for (int e = 0; e < 2; ++e) {
    const int kk = 4 * kh + e;
    const size_t base = ((size_t)((kk >> 1) * 32) + 8 * m4 + 4 * (kk & 1)) * 512;
    #pragma unroll
    for (int mt = 0; mt < 4; ++mt)
      va[e][mt] = *(const short8*)(vroot + base + mt * 512);
  }

  for (int ss = 0; ss < 16; ++ss) {
    const int buf = ss & 1;

    // ---- phase A: S/exp for this wave's 32-key group (kk = w) ----
    f32x4 s[2][4];                        // [h][nt]
    __builtin_amdgcn_s_setprio(1);
    #pragma unroll
    for (int h = 0; h < 2; ++h)
      #pragma unroll
      for (int nt = 0; nt < 4; ++nt)
        s[h][nt] = __builtin_amdgcn_mfma_f32_16x16x32_bf16(kb[h], qa[nt], zero, 0, 0, 0);
    __builtin_amdgcn_s_setprio(0);
    // prefetch next superstep's kb (in flight across barrier)
    #pragma unroll
    for (int h = 0; h < 2; ++h)
      kb[h] = *(const short8*)(kbase + (size_t)(((ss + 1) & 15) * 256 + 16 * h) * DD);

    #pragma unroll
    for (int h = 0; h < 2; ++h)
      #pragma unroll
      for (int nt = 0; nt < 4; ++nt) {
        const float e0 = fast_exp2(s[h][nt][0]);
        const float e1 = fast_exp2(s[h][nt][1]);
        const float e2 = fast_exp2(s[h][nt][2]);
        const float e3 = fast_exp2(s[h][nt][3]);
        uint2v uv;
        uv.x = __builtin_amdgcn_perm(__float_as_uint(e1), __float_as_uint(e0), 0x07060302);
        uv.y = __builtin_amdgcn_perm(__float_as_uint(e3), __float_as_uint(e2), 0x07060302);
        *(uint2v*)&sm.P[buf][w][nt][h][lane][0] = uv;   // 8B/lane: conflict-free
        l_r[nt] += (e0 + e1) + (e2 + e3);               // per-lane partial, no shuffles
      }
    BARRIER();

    // ---- phase B: PV for ch 64*m4 over kk = 4*kh .. 4*kh+3 ----
    #pragma unroll
    for (int e = 0; e < 4; ++e) {
      const int kk = 4 * kh + e;
      short8 pb[4];
      #pragma unroll
      for (int nt = 0; nt < 4; ++nt) {
        union { short8 s8; uint2v h[2]; } pbu;
        pbu.h[0] = *(const uint2v*)&sm.P[buf][kk][nt][0][lane][0];  // b64, conflict-free
        pbu.h[1] = *(const uint2v*)&sm.P[buf][kk][nt][1][lane][0];
        pb[nt] = pbu.s8;
      }
      __builtin_amdgcn_s_setprio(1);
      #pragma unroll
      for (int mt = 0; mt < 4; ++mt)
        #pragma unroll
        for (int nt = 0; nt < 4; ++nt)
          O[mt][nt] = __builtin_amdgcn_mfma_f32_16x16x32_bf16(va[e & 1][mt], pb[nt],
                                                              O[mt][nt], 0, 0, 0);
      __builtin_amdgcn_s_setprio(0);
      // refill consumed slot: e<2 -> (ss, kk+2); else -> (ss+1, 4kh + e-2)
      const int nss = (e < 2) ? ss : ((ss + 1) & 15);
      const int nkk = (e < 2) ? (kk + 2) : (4 * kh + (e - 2));
      const size_t base = ((size_t)(nss * 4 + (nkk >> 1)) * 32 + 8 * m4 + 4 * (nkk & 1)) * 512;
      #pragma unroll
      for (int mt = 0; mt < 4; ++mt)
        va[e & 1][mt] = *(const short8*)(vroot + base + mt * 512);
    }
  }

  // ---- epilogue ----
  #pragma unroll
  for (int nt = 0; nt < 4; ++nt)
    l_lds[w][nt][lane] = l_r[nt];
  BARRIER();   // all P reads done (Om may overwrite) + l_lds visible
  if (kh == 1) {
    #pragma unroll
    for (int mt = 0; mt < 4; ++mt)
      #pragma unroll
      for (int nt = 0; nt < 4; ++nt)
        *(f32x4*)&sm.Om[m4][mt * 4 + nt][lane][0] = O[mt][nt];
  }
  BARRIER();
  if (kh == 0) {
    const float gam = gamma_p[0];
    float inv_l[4];
    #pragma unroll
    for (int nt = 0; nt < 4; ++nt) {
      float s = 0.f;
      #pragma unroll
      for (int sl = 0; sl < 8; ++sl)
        #pragma unroll
        for (int g = 0; g < 4; ++g)
          s += l_lds[sl][nt][g * 16 + cl];
      inv_l[nt] = 1.0f / s;
    }
    #pragma unroll
    for (int mt = 0; mt < 4; ++mt) {
      #pragma unroll
      for (int nt = 0; nt < 4; ++nt) {
        const f32x4 om = *(const f32x4*)&sm.Om[m4][mt * 4 + nt][lane][0];
        #pragma unroll
        for (int r = 0; r < 4; ++r) {
          const int ch = 64 * m4 + 16 * mt + 4 * q4 + r;
          const int i  = i0 + 16 * nt + cl;
          const size_t idx = ((size_t)b * CC + ch) * LL + i;
          out[idx] = gam * (O[mt][nt][r] + om[r]) * inv_l[nt] + x[idx];
        }
      }
    }
  }
}

extern "C" void kernel_launch(void* const* d_in, const int* in_sizes, int n_in,
                              void* d_out, int out_size, void* d_ws, size_t ws_size,
                              hipStream_t stream) {
  const float* x     = (const float*)d_in[0];
  const float* Wq    = (const float*)d_in[1];
  const float* bq    = (const float*)d_in[2];
  const float* Wk    = (const float*)d_in[3];
  const float* bk    = (const float*)d_in[4];
  const float* Wv    = (const float*)d_in[5];
  const float* bv    = (const float*)d_in[6];
  const float* gamma = (const float*)d_in[7];
  float* out = (float*)d_out;

  // ws: qT (1MB, log2e-scaled) | kT (1MB, sigma rows) | vf (8MB, fragment-linear)
  unsigned short* qT = (unsigned short*)d_ws;
  unsigned short* kT = qT + (size_t)BB * LL * DD;
  unsigned short* vf = kT + (size_t)BB * LL * DD;
  // wf (160KB) lives in d_out; consumed by qkv, then attn overwrites d_out
  unsigned short* wf = (unsigned short*)d_out;

  wprep_kernel<<<40, 256, 0, stream>>>(Wq, Wk, Wv, wf);
  qkv_kernel<<<512, 512, 0, stream>>>(x, wf, bq, bk, bv, qT, kT, vf);
  attn_kernel<<<256, 512, 0, stream>>>(qT, kT, vf, x, gamma, out);
}